// Round 3
// baseline (492.328 us; speedup 1.0000x reference)
//
#include <hip/hip_runtime.h>
#include <hip/hip_bf16.h>

// GFNO 3D p4-equivariant conv via implicit GEMM on bf16 MFMA. R6:
//  - conv: ky-level B-slab DOUBLE BUFFER (2 x 49.4 KB LDS, 1 block/CU).
//    ky+1's 12 global_load_lds are spread 2-per-tap across taps 0..5 so the
//    vmcnt FIFO never forces an A-wait to retire the whole B queue.
//    A operand: per-lane register prefetch (1 tap deep) straight from
//    L2-resident wT -- no A LDS, no per-tap barrier. 4 barriers/block total
//    (vs 30 in R5, 108 in R3). R4's reg-A failure was the 84-VGPR regime;
//    at 1 wave/SIMD (launch_bounds(256,1)) the allocator has 512.
//  - transpose_x: __syncthreads (implicit vmcnt(0)) replaced by raw
//    s_barrier + lgkmcnt(0)-only drain; 2-row-deep register prefetch with 3
//    rotating statically-indexed slots -> HBM latency hidden under 2 full
//    pack+store phases.
//
// GEMM view: M=64 (oc), N=4*30*62*62 spatial, K=27 taps x 64 ic.
// ws layout:
//   [0, 221184)            wT  bf16 [27 tap][64 oc][64 ic]
//   [221184, 262144)       gap (tap-27 A-prefetch overrun reads this; unused)
//   [262144, +67108864)    xT  bf16 [4 nb][32 d][64 h][64 w][64 ic]

typedef __attribute__((ext_vector_type(8))) short bf16x8;
typedef __attribute__((ext_vector_type(4))) float f32x4;

__device__ __forceinline__ void gl_lds16(const void* g, void* l) {
    __builtin_amdgcn_global_load_lds(
        (const __attribute__((address_space(1))) unsigned int*)g,
        (__attribute__((address_space(3))) unsigned int*)l, 16, 0, 0);
}

// ---- symmetrized weights -> wT[tap][oc][ic] (bf16) ----------------------
__global__ __launch_bounds__(256) void build_wT(const float* __restrict__ W,
                                                __hip_bfloat16* __restrict__ wT) {
    int idx = blockIdx.x * 256 + threadIdx.x;   // (tap*64 + oc)*64 + ic
    if (idx >= 27 * 64 * 64) return;
    int ic = idx & 63;
    int oc = (idx >> 6) & 63;
    int tap = idx >> 12;
    int kt = tap % 3, kx = (tap / 3) % 3, ky = tap / 9;
    int o = oc >> 2, kc = oc & 3, i = ic >> 2, gs = ic & 3;
    int sy = ky, sx = kx;
    for (int t = 0; t < kc; ++t) {              // ws[k][g,y,x] = ws[k-1][(g-1)%4, x, 2-y]
        int ny = sx, nx = 2 - sy;
        sy = ny; sx = nx;
        gs = (gs + 3) & 3;
    }
    wT[idx] = __float2bfloat16(W[((o * 16 + i) * 4 + gs) * 27 + sy * 9 + sx * 3 + kt]);
}

// ---- x (NCDHW fp32) -> xT[nb][d][h][w][ic] (bf16) -----------------------
__device__ __forceinline__ unsigned int pack2(float a, float b) {
    union { __hip_bfloat162 h2; unsigned int u; } c;
    c.h2 = __hip_bfloat162{__float2bfloat16(a), __float2bfloat16(b)};
    return c.u;
}

__global__ __launch_bounds__(256) void transpose_x(const float* __restrict__ x,
                                                   __hip_bfloat16* __restrict__ xT) {
    __shared__ unsigned int ls[64 * 37];   // [w][ic/2] bf16x2, stride 37 (conflict-free)
    int bid = blockIdx.x;                  // (nb*32 + d)*8 + hq
    int hq = bid & 7, d = (bid >> 3) & 31, nb = bid >> 8;
    int tid = threadIdx.x;
    int w4 = tid & 15;                     // float4 index along w
    int kp = tid >> 4;                     // 0..15

    float4 a[3][2], b[3][2];               // 3 rotating row slots (static idx)
#define LOADROW(s, hh) do {                                                          \
    const float* s0_ = x + ((((size_t)nb * 64 + 2 * kp) * 32 + d) * 64 + (hh)) * 64 + w4 * 4;        \
    const float* s1_ = x + ((((size_t)nb * 64 + 2 * (16 + kp)) * 32 + d) * 64 + (hh)) * 64 + w4 * 4; \
    a[s][0] = *(const float4*)s0_; b[s][0] = *(const float4*)(s0_ + 131072);         \
    a[s][1] = *(const float4*)s1_; b[s][1] = *(const float4*)(s1_ + 131072);         \
} while (0)

    LOADROW(0, hq * 8 + 0);
    LOADROW(1, hq * 8 + 1);
#pragma unroll
    for (int hi = 0; hi < 8; ++hi) {
        const int sc = hi % 3, sn = (hi + 2) % 3;
        // LDS handoff barrier: drain ds ops only -- global prefetch stays in flight
        asm volatile("s_waitcnt lgkmcnt(0)" ::: "memory");
        __builtin_amdgcn_s_barrier();
        if (hi < 6) LOADROW(sn, hq * 8 + hi + 2);
#pragma unroll
        for (int r = 0; r < 2; ++r) {      // pack waits vmcnt for slot sc only (FIFO-safe)
            int p = r * 16 + kp;
            ls[(w4 * 4 + 0) * 37 + p] = pack2(a[sc][r].x, b[sc][r].x);
            ls[(w4 * 4 + 1) * 37 + p] = pack2(a[sc][r].y, b[sc][r].y);
            ls[(w4 * 4 + 2) * 37 + p] = pack2(a[sc][r].z, b[sc][r].z);
            ls[(w4 * 4 + 3) * 37 + p] = pack2(a[sc][r].w, b[sc][r].w);
        }
        asm volatile("s_waitcnt lgkmcnt(0)" ::: "memory");
        __builtin_amdgcn_s_barrier();
        __hip_bfloat16* obase = xT + (((size_t)nb * 32 + d) * 64 + (hq * 8 + hi)) * 4096;
#pragma unroll
        for (int c = tid; c < 512; c += 256) {
            int ww = c >> 3, icc = c & 7;
            const unsigned int* q = ls + ww * 37 + icc * 4;
            uint4 v;
            v.x = q[0]; v.y = q[1]; v.z = q[2]; v.w = q[3];
            *(uint4*)(obase + ww * 64 + icc * 8) = v;
        }
    }
#undef LOADROW
}

// ---- implicit GEMM conv -------------------------------------------------
// block: 64 oc x 256 spatial (4 h-rows x 64 w), wave w owns h-row w.
// B: ky-level 48KB slab dbuf, next-ky segs spread 2/tap over taps 0..5.
// A: per-lane register prefetch from wT (identical frags in all 4 waves; L1
//    absorbs the redundancy). Barriers: 1 prologue + 1 per ky.
__global__ __launch_bounds__(256, 1) void conv_mfma(const __hip_bfloat16* __restrict__ xT,
                                                    const __hip_bfloat16* __restrict__ wT,
                                                    const float* __restrict__ Bp,
                                                    float* __restrict__ out) {
    __shared__ __align__(16) short sB[2][6 * 4096 + 128];   // 2 x 49,408 B

    int orig = blockIdx.x;                     // 1920 blocks, 1920 % 8 == 0
    int bid = (orig & 7) * 240 + (orig >> 3);  // bijective XCD swizzle
    int ht = bid % 16;                 // h-tile of 4 rows
    int d  = (bid / 16) % 30;
    int nb = bid / 480;
    int h0 = ht * 4;

    int tid = threadIdx.x;
    int w = tid >> 6;                  // wave id = h-row
    int lane = tid & 63;
    int quad = lane >> 4, col = lane & 15;

    f32x4 acc[4][4];
#pragma unroll
    for (int mt = 0; mt < 4; ++mt)
#pragma unroll
        for (int nt = 0; nt < 4; ++nt) acc[mt][nt] = (f32x4)(0.0f);

    // pre-swizzled per-lane source offset (shorts) for B staging:
    // LDS[row r][chunk c] = G[row r][chunk c ^ (r&7)]  (row=128B, chunk=16B)
    int srcl = ((lane >> 3) << 6) + (((lane & 7) ^ (lane >> 3)) << 3);

    const __hip_bfloat16* xb = xT + (size_t)nb * 8388608 + (size_t)d * 262144;
    const __hip_bfloat16* aT = wT + col * 64 + quad * 8;   // + g*4096 + mt*1024 + ich*32

    // prologue: stage full B slab for ky=0, load A frags for tap 0
#pragma unroll
    for (int i = 0; i < 12; ++i) {
        int p = w + i * 4;                 // seg: row = p>>3, j = p&7
        int hh = h0 + (p >> 3);
        if (hh > 63) hh = 63;              // clamped rows feed only discarded outputs
        gl_lds16(xb + hh * 4096 + (p & 7) * 512 + srcl, (char*)sB[0] + p * 1024);
    }
    bf16x8 afc[4][2], afn[4][2];
#pragma unroll
    for (int mt = 0; mt < 4; ++mt)
#pragma unroll
        for (int ich = 0; ich < 2; ++ich)
            afc[mt][ich] = *(const bf16x8*)(aT + mt * 1024 + ich * 32);
    __syncthreads();                       // slab + A0 landed (vmcnt0, once)

    for (int ky = 0; ky < 3; ++ky) {
        const short* sBc = sB[ky & 1];
        char* sBn = (char*)sB[(ky + 1) & 1];
        const __hip_bfloat16* xn = xb + (size_t)(ky + 1) * 262144;

#pragma unroll
        for (int t = 0; t < 9; ++t) {
            int g = ky * 9 + t;
            // A prefetch for tap g+1 (g=26 reads the ws gap past wT; unused)
#pragma unroll
            for (int mt = 0; mt < 4; ++mt)
#pragma unroll
                for (int ich = 0; ich < 2; ++ich)
                    afn[mt][ich] = *(const bf16x8*)(aT + (g + 1) * 4096
                                                    + mt * 1024 + ich * 32);
            // B slab prefetch for ky+1: 2 segs/tap on taps 0..5 (spread keeps
            // the vmcnt FIFO short so A waits don't retire the B queue)
            if (ky < 2 && t < 6) {
#pragma unroll
                for (int i = 0; i < 2; ++i) {
                    int p = w + (t * 2 + i) * 4;
                    int hh = h0 + (p >> 3);
                    if (hh > 63) hh = 63;
                    gl_lds16(xn + hh * 4096 + (p & 7) * 512 + srcl, sBn + p * 1024);
                }
            }

            const int kt = t % 3, kx = t / 3;
            int wc = col + kt;
            const short* pb = sBc + ((w + kx) * 64 + wc) * 64;
            int bswz = (quad * 8) ^ ((wc & 7) << 3);
#pragma unroll
            for (int ich = 0; ich < 2; ++ich) {
                bf16x8 bfr[4];
#pragma unroll
                for (int nt = 0; nt < 4; ++nt)
                    bfr[nt] = *(const bf16x8*)(pb + ((ich * 32) ^ bswz) + nt * 1024);
#pragma unroll
                for (int mt = 0; mt < 4; ++mt)
#pragma unroll
                    for (int nt = 0; nt < 4; ++nt)
                        acc[mt][nt] = __builtin_amdgcn_mfma_f32_16x16x32_bf16(
                            afc[mt][ich], bfr[nt], acc[mt][nt], 0, 0, 0);
            }
#pragma unroll
            for (int mt = 0; mt < 4; ++mt)
#pragma unroll
                for (int ich = 0; ich < 2; ++ich)
                    afc[mt][ich] = afn[mt][ich];
        }
        __syncthreads();   // ky+1 slab landed; current slab reads done before
                           // ky+2's overwrite (issued after this barrier)
    }

    // epilogue: D row = quad*4 + r (oc), col = n
    int hrow = h0 + w;
    if (hrow < 62) {
#pragma unroll
        for (int mt = 0; mt < 4; ++mt) {
            float bias = Bp[mt * 4 + quad];
#pragma unroll
            for (int nt = 0; nt < 4; ++nt) {
                int wp = nt * 16 + col;
                if (wp < 62) {
#pragma unroll
                    for (int r = 0; r < 4; ++r) {
                        int oc = mt * 16 + quad * 4 + r;
                        out[(((size_t)nb * 64 + oc) * 30 + d) * 3844 + hrow * 62 + wp]
                            = acc[mt][nt][r] + bias;
                    }
                }
            }
        }
    }
}

extern "C" void kernel_launch(void* const* d_in, const int* in_sizes, int n_in,
                              void* d_out, int out_size, void* d_ws, size_t ws_size,
                              hipStream_t stream) {
    const float* x = (const float*)d_in[0];
    const float* W = (const float*)d_in[1];
    const float* Bp = (const float*)d_in[2];
    float* out = (float*)d_out;

    char* ws = (char*)d_ws;
    __hip_bfloat16* wT = (__hip_bfloat16*)ws;              // 221,184 B
    __hip_bfloat16* xT = (__hip_bfloat16*)(ws + 262144);   // 67,108,864 B

    build_wT<<<(27 * 64 * 64 + 255) / 256, 256, 0, stream>>>(W, wT);
    transpose_x<<<4 * 32 * 8, 256, 0, stream>>>(x, xT);
    conv_mfma<<<4 * 30 * 16, 256, 0, stream>>>(xT, wT, Bp, out);
}

// Round 4
// 327.435 us; speedup vs baseline: 1.5036x; 1.5036x over previous
//
#include <hip/hip_runtime.h>
#include <hip/hip_bf16.h>

// GFNO 3D p4-equivariant conv via implicit GEMM on bf16 MFMA. R7:
//  Revert to R5 skeleton (verified 120.8us: 2 blocks/CU, B slab/ky in LDS,
//  A staged via LDS) -- R6's 1-block/CU + per-lane-global-A regressed 2.4x
//  (1 wave/SIMD = no TLP; compiler won't pipeline per-lane A loads).
//  Surgical upgrade: counted-vmcnt pipeline (T4):
//   - A staging deepened to a 3-slot rotating LDS buffer (24KB). At tap g the
//     wave issues A[g+2], waits s_waitcnt vmcnt(2) (retires A[g], issued 2
//     taps ~800cyc ago; leaves A[g+1],A[g+2] in flight), raw s_barrier.
//     No more per-tap vmcnt(0) drain of just-issued loads (R5's stall).
//   - ky-boundary: double barrier around the 48KB slab fill (3 exposed
//     fills/block remain).
//   - g-loop fully unrolled: slot indices and wait immediates static;
//     sched_barrier(0) after each barrier (rule 18).
//  LDS = 49408 + 24576 = 73984 B -> 2 blocks/CU.
//
// GEMM view: M=64 (oc), N=4*30*62*62 spatial, K=27 taps x 64 ic.
// ws layout:
//   [0, 221184)            wT  bf16 [27 tap][64 oc][64 ic]
//   [262144, +67108864)    xT  bf16 [4 nb][32 d][64 h][64 w][64 ic]

typedef __attribute__((ext_vector_type(8))) short bf16x8;
typedef __attribute__((ext_vector_type(4))) float f32x4;

__device__ __forceinline__ void gl_lds16(const void* g, void* l) {
    __builtin_amdgcn_global_load_lds(
        (const __attribute__((address_space(1))) unsigned int*)g,
        (__attribute__((address_space(3))) unsigned int*)l, 16, 0, 0);
}

#define WAITV(n) asm volatile("s_waitcnt vmcnt(" #n ")" ::: "memory")

// ---- symmetrized weights -> wT[tap][oc][ic] (bf16) ----------------------
__global__ __launch_bounds__(256) void build_wT(const float* __restrict__ W,
                                                __hip_bfloat16* __restrict__ wT) {
    int idx = blockIdx.x * 256 + threadIdx.x;   // (tap*64 + oc)*64 + ic
    if (idx >= 27 * 64 * 64) return;
    int ic = idx & 63;
    int oc = (idx >> 6) & 63;
    int tap = idx >> 12;
    int kt = tap % 3, kx = (tap / 3) % 3, ky = tap / 9;
    int o = oc >> 2, kc = oc & 3, i = ic >> 2, gs = ic & 3;
    int sy = ky, sx = kx;
    for (int t = 0; t < kc; ++t) {              // ws[k][g,y,x] = ws[k-1][(g-1)%4, x, 2-y]
        int ny = sx, nx = 2 - sy;
        sy = ny; sx = nx;
        gs = (gs + 3) & 3;
    }
    wT[idx] = __float2bfloat16(W[((o * 16 + i) * 4 + gs) * 27 + sy * 9 + sx * 3 + kt]);
}

// ---- x (NCDHW fp32) -> xT[nb][d][h][w][ic] (bf16) -----------------------
__device__ __forceinline__ unsigned int pack2(float a, float b) {
    union { __hip_bfloat162 h2; unsigned int u; } c;
    c.h2 = __hip_bfloat162{__float2bfloat16(a), __float2bfloat16(b)};
    return c.u;
}

__global__ __launch_bounds__(256) void transpose_x(const float* __restrict__ x,
                                                   __hip_bfloat16* __restrict__ xT) {
    __shared__ unsigned int ls[64 * 37];   // [w][ic/2] bf16x2, stride 37 (conflict-free)
    int bid = blockIdx.x;                  // (nb*32 + d)*8 + hq
    int hq = bid & 7, d = (bid >> 3) & 31, nb = bid >> 8;
    int tid = threadIdx.x;
    int w4 = tid & 15;                     // float4 index along w
    int kp = tid >> 4;                     // 0..15

    float4 a[3][2], b[3][2];               // 3 rotating row slots (static idx)
#define LOADROW(s, hh) do {                                                          \
    const float* s0_ = x + ((((size_t)nb * 64 + 2 * kp) * 32 + d) * 64 + (hh)) * 64 + w4 * 4;        \
    const float* s1_ = x + ((((size_t)nb * 64 + 2 * (16 + kp)) * 32 + d) * 64 + (hh)) * 64 + w4 * 4; \
    a[s][0] = *(const float4*)s0_; b[s][0] = *(const float4*)(s0_ + 131072);         \
    a[s][1] = *(const float4*)s1_; b[s][1] = *(const float4*)(s1_ + 131072);         \
} while (0)

    LOADROW(0, hq * 8 + 0);
    LOADROW(1, hq * 8 + 1);
#pragma unroll
    for (int hi = 0; hi < 8; ++hi) {
        const int sc = hi % 3, sn = (hi + 2) % 3;
        // LDS handoff barrier: drain ds ops only -- global prefetch stays in flight
        asm volatile("s_waitcnt lgkmcnt(0)" ::: "memory");
        __builtin_amdgcn_s_barrier();
        if (hi < 6) LOADROW(sn, hq * 8 + hi + 2);
#pragma unroll
        for (int r = 0; r < 2; ++r) {      // pack waits vmcnt for slot sc only (FIFO-safe)
            int p = r * 16 + kp;
            ls[(w4 * 4 + 0) * 37 + p] = pack2(a[sc][r].x, b[sc][r].x);
            ls[(w4 * 4 + 1) * 37 + p] = pack2(a[sc][r].y, b[sc][r].y);
            ls[(w4 * 4 + 2) * 37 + p] = pack2(a[sc][r].z, b[sc][r].z);
            ls[(w4 * 4 + 3) * 37 + p] = pack2(a[sc][r].w, b[sc][r].w);
        }
        asm volatile("s_waitcnt lgkmcnt(0)" ::: "memory");
        __builtin_amdgcn_s_barrier();
        __hip_bfloat16* obase = xT + (((size_t)nb * 32 + d) * 64 + (hq * 8 + hi)) * 4096;
#pragma unroll
        for (int c = tid; c < 512; c += 256) {
            int ww = c >> 3, icc = c & 7;
            const unsigned int* q = ls + ww * 37 + icc * 4;
            uint4 v;
            v.x = q[0]; v.y = q[1]; v.z = q[2]; v.w = q[3];
            *(uint4*)(obase + ww * 64 + icc * 8) = v;
        }
    }
#undef LOADROW
}

// ---- implicit GEMM conv -------------------------------------------------
// block: 64 oc x 256 spatial (4 h-rows x 64 w), wave w owns h-row w.
// B: 48KB slab per ky (single-buffered, boundary double-barrier).
// A: 3-slot rotating LDS pipeline, counted vmcnt(2) waits, raw s_barrier.
__global__ __launch_bounds__(256, 2) void conv_mfma(const __hip_bfloat16* __restrict__ xT,
                                                    const __hip_bfloat16* __restrict__ wT,
                                                    const float* __restrict__ Bp,
                                                    float* __restrict__ out) {
    __shared__ __align__(16) short sB[6 * 4096 + 128];   // 49,408 B (+kt slack)
    __shared__ __align__(16) short sA[3 * 4096];         // 24,576 B (3-slot A)

    int orig = blockIdx.x;                     // 1920 blocks, 1920 % 8 == 0
    int bid = (orig & 7) * 240 + (orig >> 3);  // bijective XCD swizzle
    int ht = bid % 16;                 // h-tile of 4 rows
    int d  = (bid / 16) % 30;
    int nb = bid / 480;
    int h0 = ht * 4;

    int tid = threadIdx.x;
    int w = tid >> 6;                  // wave id = h-row
    int lane = tid & 63;
    int quad = lane >> 4, col = lane & 15;

    f32x4 acc[4][4];
#pragma unroll
    for (int mt = 0; mt < 4; ++mt)
#pragma unroll
        for (int nt = 0; nt < 4; ++nt) acc[mt][nt] = (f32x4)(0.0f);

    // pre-swizzled per-lane source offset (shorts), shared by A and B staging:
    // LDS[row r][chunk c] = G[row r][chunk c ^ (r&7)]  (row=128B, chunk=16B)
    int srcl = ((lane >> 3) << 6) + (((lane & 7) ^ (lane >> 3)) << 3);

    const __hip_bfloat16* xb = xT + (size_t)nb * 8388608 + (size_t)d * 262144;

    // prologue: slab ky0 (12 segs/wave), A[0]->slot0, A[1]->slot1
#pragma unroll
    for (int i = 0; i < 12; ++i) {
        int p = w + i * 4;                 // seg: row = p>>3, j = p&7
        int hh = h0 + (p >> 3);
        if (hh > 63) hh = 63;              // clamped rows feed only discarded outputs
        gl_lds16(xb + hh * 4096 + (p & 7) * 512 + srcl, (char*)sB + p * 1024);
    }
#pragma unroll
    for (int a = 0; a < 2; ++a)
#pragma unroll
        for (int i = 0; i < 2; ++i)
            gl_lds16(wT + a * 4096 + (w * 2 + i) * 512 + srcl,
                     (char*)sA + a * 8192 + (w * 2 + i) * 1024);
    WAITV(2);                              // slab + A0 landed; A1 in flight
    __builtin_amdgcn_s_barrier();
    __builtin_amdgcn_sched_barrier(0);

#pragma unroll
    for (int g = 0; g < 27; ++g) {
        const int ky = g / 9, t = g % 9;
        const int kt = t % 3, kx = t / 3;
        const int slot = g % 3;

        if (g > 0) {                       // (g==0's wait/barrier is the prologue's)
            if (g == 26) { WAITV(0); }     // last A has nothing behind it
            else         { WAITV(2); }     // retire A[g]; keep A[g+1](,A[g+2])
            __builtin_amdgcn_s_barrier();  // all waves: A[g] visible, slot/slab reads done
            __builtin_amdgcn_sched_barrier(0);
        }

        if (t == 0 && ky > 0) {            // stage this ky's slab (reads done per barrier)
            const __hip_bfloat16* xcur = xb + (size_t)ky * 262144;
#pragma unroll
            for (int i = 0; i < 12; ++i) {
                int p = w + i * 4;
                int hh = h0 + (p >> 3);
                if (hh > 63) hh = 63;
                gl_lds16(xcur + hh * 4096 + (p & 7) * 512 + srcl, (char*)sB + p * 1024);
            }
        }
        if (g + 2 <= 26) {                 // issue A[g+2] -> slot (g+2)%3
#pragma unroll
            for (int i = 0; i < 2; ++i)
                gl_lds16(wT + (g + 2) * 4096 + (w * 2 + i) * 512 + srcl,
                         (char*)sA + ((g + 2) % 3) * 8192 + (w * 2 + i) * 1024);
        }
        if (t == 0 && ky > 0) {            // slab landed (leaves A[g+2] in flight)
            WAITV(2);
            __builtin_amdgcn_s_barrier();
            __builtin_amdgcn_sched_barrier(0);
        }

        // compute tap g
        const short* aBase = sA + slot * 4096;
        int wc = col + kt;
        const short* pb = sB + ((w + kx) * 64 + wc) * 64;
        int bswz = (quad * 8) ^ ((wc & 7) << 3);
#pragma unroll
        for (int ich = 0; ich < 2; ++ich) {
            bf16x8 af[4], bfr[4];
#pragma unroll
            for (int mt = 0; mt < 4; ++mt)
                af[mt] = *(const bf16x8*)(aBase + col * 64 + mt * 1024
                                          + (((ich * 4 + quad) ^ (col & 7)) << 3));
#pragma unroll
            for (int nt = 0; nt < 4; ++nt)
                bfr[nt] = *(const bf16x8*)(pb + ((ich * 32) ^ bswz) + nt * 1024);

            __builtin_amdgcn_s_setprio(1);
#pragma unroll
            for (int mt = 0; mt < 4; ++mt)
#pragma unroll
                for (int nt = 0; nt < 4; ++nt)
                    acc[mt][nt] = __builtin_amdgcn_mfma_f32_16x16x32_bf16(
                        af[mt], bfr[nt], acc[mt][nt], 0, 0, 0);
            __builtin_amdgcn_s_setprio(0);
        }
    }

    // epilogue: D row = quad*4 + r (oc), col = n
    int hrow = h0 + w;
    if (hrow < 62) {
#pragma unroll
        for (int mt = 0; mt < 4; ++mt) {
            float bias = Bp[mt * 4 + quad];
#pragma unroll
            for (int nt = 0; nt < 4; ++nt) {
                int wp = nt * 16 + col;
                if (wp < 62) {
#pragma unroll
                    for (int r = 0; r < 4; ++r) {
                        int oc = mt * 16 + quad * 4 + r;
                        out[(((size_t)nb * 64 + oc) * 30 + d) * 3844 + hrow * 62 + wp]
                            = acc[mt][nt][r] + bias;
                    }
                }
            }
        }
    }
}

extern "C" void kernel_launch(void* const* d_in, const int* in_sizes, int n_in,
                              void* d_out, int out_size, void* d_ws, size_t ws_size,
                              hipStream_t stream) {
    const float* x = (const float*)d_in[0];
    const float* W = (const float*)d_in[1];
    const float* Bp = (const float*)d_in[2];
    float* out = (float*)d_out;

    char* ws = (char*)d_ws;
    __hip_bfloat16* wT = (__hip_bfloat16*)ws;              // 221,184 B
    __hip_bfloat16* xT = (__hip_bfloat16*)(ws + 262144);   // 67,108,864 B

    build_wT<<<(27 * 64 * 64 + 255) / 256, 256, 0, stream>>>(W, wT);
    transpose_x<<<4 * 32 * 8, 256, 0, stream>>>(x, xT);
    conv_mfma<<<4 * 30 * 16, 256, 0, stream>>>(xT, wT, Bp, out);
}

// Round 6
// 326.661 us; speedup vs baseline: 1.5072x; 1.0024x over previous
//
#include <hip/hip_runtime.h>
#include <hip/hip_bf16.h>

// GFNO 3D p4-equivariant conv via implicit GEMM on bf16 MFMA. R9:
//  R7 skeleton (verified 117us: 2 blocks/CU, per-ky 48KB B slab, 3-slot A
//  LDS pipeline, raw s_barrier). R8's s_sleep kick removed (bench crashed).
//  New: INTRA-WAVE FRAGMENT PREFETCH. R7 counters showed per-tap time =
//  DS floor (1536cyc) + MFMA floor (1242cyc) exactly serial. Now tap g
//  issues the 16 ds_read_b128 for tap g+1's fragments BEFORE tap g's 32
//  MFMAs (sched_barrier-pinned) into a parity-indexed register set
//  f[2][..] (indices fold after full unroll). MFMAs wait lgkmcnt only on
//  cur frags (DS retires in-order); next's reads drain under the MFMAs.
//  Per-tap wait deepened to vmcnt(0) -- free now, since the only
//  outstanding load (A[g+1]) was issued a full tap (~1500cyc) earlier --
//  and required so A[g+1] is published before its frags are prefetched.
//  Boundary taps (t==0; slab rewritten) read inline: 3 of 27 exposed.
//
// GEMM view: M=64 (oc), N=4*30*62*62 spatial, K=27 taps x 64 ic.
// ws layout:
//   [0, 221184)            wT  bf16 [27 tap][64 oc][64 ic]
//   [262144, +67108864)    xT  bf16 [4 nb][32 d][64 h][64 w][64 ic]

typedef __attribute__((ext_vector_type(8))) short bf16x8;
typedef __attribute__((ext_vector_type(4))) float f32x4;

__device__ __forceinline__ void gl_lds16(const void* g, void* l) {
    __builtin_amdgcn_global_load_lds(
        (const __attribute__((address_space(1))) unsigned int*)g,
        (__attribute__((address_space(3))) unsigned int*)l, 16, 0, 0);
}

#define WAITV(n) asm volatile("s_waitcnt vmcnt(" #n ")" ::: "memory")

// ---- symmetrized weights -> wT[tap][oc][ic] (bf16) ----------------------
__global__ __launch_bounds__(256) void build_wT(const float* __restrict__ W,
                                                __hip_bfloat16* __restrict__ wT) {
    int idx = blockIdx.x * 256 + threadIdx.x;   // (tap*64 + oc)*64 + ic
    if (idx >= 27 * 64 * 64) return;
    int ic = idx & 63;
    int oc = (idx >> 6) & 63;
    int tap = idx >> 12;
    int kt = tap % 3, kx = (tap / 3) % 3, ky = tap / 9;
    int o = oc >> 2, kc = oc & 3, i = ic >> 2, gs = ic & 3;
    int sy = ky, sx = kx;
    for (int t = 0; t < kc; ++t) {              // ws[k][g,y,x] = ws[k-1][(g-1)%4, x, 2-y]
        int ny = sx, nx = 2 - sy;
        sy = ny; sx = nx;
        gs = (gs + 3) & 3;
    }
    wT[idx] = __float2bfloat16(W[((o * 16 + i) * 4 + gs) * 27 + sy * 9 + sx * 3 + kt]);
}

// ---- x (NCDHW fp32) -> xT[nb][d][h][w][ic] (bf16) -----------------------
__device__ __forceinline__ unsigned int pack2(float a, float b) {
    union { __hip_bfloat162 h2; unsigned int u; } c;
    c.h2 = __hip_bfloat162{__float2bfloat16(a), __float2bfloat16(b)};
    return c.u;
}

__global__ __launch_bounds__(256) void transpose_x(const float* __restrict__ x,
                                                   __hip_bfloat16* __restrict__ xT) {
    __shared__ unsigned int ls[64 * 37];   // [w][ic/2] bf16x2, stride 37 (conflict-free)
    int bid = blockIdx.x;                  // (nb*32 + d)*8 + hq
    int hq = bid & 7, d = (bid >> 3) & 31, nb = bid >> 8;
    int tid = threadIdx.x;
    int w4 = tid & 15;                     // float4 index along w
    int kp = tid >> 4;                     // 0..15

    float4 a[3][2], b[3][2];               // 3 rotating row slots (static idx)
#define LOADROW(s, hh) do {                                                          \
    const float* s0_ = x + ((((size_t)nb * 64 + 2 * kp) * 32 + d) * 64 + (hh)) * 64 + w4 * 4;        \
    const float* s1_ = x + ((((size_t)nb * 64 + 2 * (16 + kp)) * 32 + d) * 64 + (hh)) * 64 + w4 * 4; \
    a[s][0] = *(const float4*)s0_; b[s][0] = *(const float4*)(s0_ + 131072);         \
    a[s][1] = *(const float4*)s1_; b[s][1] = *(const float4*)(s1_ + 131072);         \
} while (0)

    LOADROW(0, hq * 8 + 0);
    LOADROW(1, hq * 8 + 1);
#pragma unroll
    for (int hi = 0; hi < 8; ++hi) {
        const int sc = hi % 3, sn = (hi + 2) % 3;
        // LDS handoff barrier: drain ds ops only -- global prefetch stays in flight
        asm volatile("s_waitcnt lgkmcnt(0)" ::: "memory");
        __builtin_amdgcn_s_barrier();
        if (hi < 6) LOADROW(sn, hq * 8 + hi + 2);
#pragma unroll
        for (int r = 0; r < 2; ++r) {      // pack waits vmcnt for slot sc only (FIFO-safe)
            int p = r * 16 + kp;
            ls[(w4 * 4 + 0) * 37 + p] = pack2(a[sc][r].x, b[sc][r].x);
            ls[(w4 * 4 + 1) * 37 + p] = pack2(a[sc][r].y, b[sc][r].y);
            ls[(w4 * 4 + 2) * 37 + p] = pack2(a[sc][r].z, b[sc][r].z);
            ls[(w4 * 4 + 3) * 37 + p] = pack2(a[sc][r].w, b[sc][r].w);
        }
        asm volatile("s_waitcnt lgkmcnt(0)" ::: "memory");
        __builtin_amdgcn_s_barrier();
        __hip_bfloat16* obase = xT + (((size_t)nb * 32 + d) * 64 + (hq * 8 + hi)) * 4096;
#pragma unroll
        for (int c = tid; c < 512; c += 256) {
            int ww = c >> 3, icc = c & 7;
            const unsigned int* q = ls + ww * 37 + icc * 4;
            uint4 v;
            v.x = q[0]; v.y = q[1]; v.z = q[2]; v.w = q[3];
            *(uint4*)(obase + ww * 64 + icc * 8) = v;
        }
    }
#undef LOADROW
}

// ---- implicit GEMM conv -------------------------------------------------
// block: 64 oc x 256 spatial (4 h-rows x 64 w), wave w owns h-row w.
// B: 48KB slab per ky (single-buffered, boundary double-barrier).
// A: 3-slot rotating LDS pipeline. Fragments register-prefetched 1 tap ahead.
__global__ __launch_bounds__(256, 2) void conv_mfma(const __hip_bfloat16* __restrict__ xT,
                                                    const __hip_bfloat16* __restrict__ wT,
                                                    const float* __restrict__ Bp,
                                                    float* __restrict__ out) {
    __shared__ __align__(16) short sB[6 * 4096 + 128];   // 49,408 B (+kt slack)
    __shared__ __align__(16) short sA[3 * 4096];         // 24,576 B (3-slot A)

    int orig = blockIdx.x;                     // 1920 blocks, 1920 % 8 == 0
    int bid = (orig & 7) * 240 + (orig >> 3);  // bijective XCD swizzle
    int ht = bid % 16;                 // h-tile of 4 rows
    int d  = (bid / 16) % 30;
    int nb = bid / 480;
    int h0 = ht * 4;

    int tid = threadIdx.x;
    int w = tid >> 6;                  // wave id = h-row
    int lane = tid & 63;
    int quad = lane >> 4, col = lane & 15;

    f32x4 acc[4][4];
#pragma unroll
    for (int mt = 0; mt < 4; ++mt)
#pragma unroll
        for (int nt = 0; nt < 4; ++nt) acc[mt][nt] = (f32x4)(0.0f);

    // pre-swizzled per-lane source offset (shorts), shared by A and B staging:
    // LDS[row r][chunk c] = G[row r][chunk c ^ (r&7)]  (row=128B, chunk=16B)
    int srcl = ((lane >> 3) << 6) + (((lane & 7) ^ (lane >> 3)) << 3);

    const __hip_bfloat16* xb = xT + (size_t)nb * 8388608 + (size_t)d * 262144;

    // prologue: slab ky0 (12 segs/wave), A[0]->slot0, A[1]->slot1
#pragma unroll
    for (int i = 0; i < 12; ++i) {
        int p = w + i * 4;                 // seg: row = p>>3, j = p&7
        int hh = h0 + (p >> 3);
        if (hh > 63) hh = 63;              // clamped rows feed only discarded outputs
        gl_lds16(xb + hh * 4096 + (p & 7) * 512 + srcl, (char*)sB + p * 1024);
    }
#pragma unroll
    for (int a = 0; a < 2; ++a)
#pragma unroll
        for (int i = 0; i < 2; ++i)
            gl_lds16(wT + a * 4096 + (w * 2 + i) * 512 + srcl,
                     (char*)sA + a * 8192 + (w * 2 + i) * 1024);
    WAITV(0);                              // slab + A0 + A1 all landed
    __builtin_amdgcn_s_barrier();
    __builtin_amdgcn_sched_barrier(0);

    // fragment registers, parity-indexed: tap g lives in f*[g&1] (indices
    // fold after full unroll; rule 20)
    bf16x8 fa[2][4][2], fb[2][4][2];

    // READ_FRAGS(q, p): load tap q's A/B fragments into fa[p]/fb[p]
#define READ_FRAGS(q, p) do {                                                   \
    const int kt_ = ((q) % 9) % 3, kx_ = ((q) % 9) / 3;                         \
    const short* aB_ = sA + ((q) % 3) * 4096;                                   \
    const int wc_ = col + kt_;                                                  \
    const short* pb_ = sB + ((w + kx_) * 64 + wc_) * 64;                        \
    const int bs_ = (quad * 8) ^ ((wc_ & 7) << 3);                              \
    _Pragma("unroll") for (int ich_ = 0; ich_ < 2; ++ich_) {                    \
        _Pragma("unroll") for (int mt_ = 0; mt_ < 4; ++mt_)                     \
            fa[p][mt_][ich_] = *(const bf16x8*)(aB_ + col * 64 + mt_ * 1024     \
                                + (((ich_ * 4 + quad) ^ (col & 7)) << 3));      \
        _Pragma("unroll") for (int nt_ = 0; nt_ < 4; ++nt_)                     \
            fb[p][nt_][ich_] = *(const bf16x8*)(pb_ + ((ich_ * 32) ^ bs_)       \
                                + nt_ * 1024);                                  \
    }                                                                           \
} while (0)

#pragma unroll
    for (int g = 0; g < 27; ++g) {
        const int ky = g / 9, t = g % 9;
        const int cp = g & 1, np = cp ^ 1;

        // --- sync / stage phase ---
        if (g == 0) {
            // prologue did wait+barrier; issue A[2] -> slot 2
#pragma unroll
            for (int i = 0; i < 2; ++i)
                gl_lds16(wT + 2 * 4096 + (w * 2 + i) * 512 + srcl,
                         (char*)sA + 2 * 8192 + (w * 2 + i) * 1024);
        } else if (t == 0) {               // g = 9, 18: re-stage B slab
            WAITV(0);                      // retires A[g+1] (issued 1 tap ago)
            __builtin_amdgcn_s_barrier();
            __builtin_amdgcn_sched_barrier(0);
            const __hip_bfloat16* xcur = xb + (size_t)ky * 262144;
#pragma unroll
            for (int i = 0; i < 12; ++i) {
                int p = w + i * 4;
                int hh = h0 + (p >> 3);
                if (hh > 63) hh = 63;
                gl_lds16(xcur + hh * 4096 + (p & 7) * 512 + srcl, (char*)sB + p * 1024);
            }
#pragma unroll
            for (int i = 0; i < 2; ++i)    // A[g+2] -> slot (g+2)%3
                gl_lds16(wT + (g + 2) * 4096 + (w * 2 + i) * 512 + srcl,
                         (char*)sA + ((g + 2) % 3) * 8192 + (w * 2 + i) * 1024);
            WAITV(2);                      // slab landed; A[g+2] stays in flight
            __builtin_amdgcn_s_barrier();
            __builtin_amdgcn_sched_barrier(0);
        } else if (g < 26) {
            WAITV(0);                      // retires A[g+1] (issued 1 tap ago)
            __builtin_amdgcn_s_barrier();
            __builtin_amdgcn_sched_barrier(0);
            if (g + 2 <= 26) {
#pragma unroll
                for (int i = 0; i < 2; ++i)
                    gl_lds16(wT + (g + 2) * 4096 + (w * 2 + i) * 512 + srcl,
                             (char*)sA + ((g + 2) % 3) * 8192 + (w * 2 + i) * 1024);
            }
        }
        // g == 26: nothing outstanding, no LDS-write hazards -> no sync

        // --- inline cur-frag read at boundary taps (no prefetch possible) ---
        if (t == 0) READ_FRAGS(g, cp);

        // --- prefetch next tap's frags (skip if next is boundary or none) ---
        if (g < 26 && t != 8) READ_FRAGS(g + 1, np);

        __builtin_amdgcn_sched_barrier(0); // pin: prefetch issued before MFMAs

        // --- MFMA on cur frags (lgkmcnt waits only for cur; next drains under) ---
        __builtin_amdgcn_s_setprio(1);
#pragma unroll
        for (int ich = 0; ich < 2; ++ich)
#pragma unroll
            for (int mt = 0; mt < 4; ++mt)
#pragma unroll
                for (int nt = 0; nt < 4; ++nt)
                    acc[mt][nt] = __builtin_amdgcn_mfma_f32_16x16x32_bf16(
                        fa[cp][mt][ich], fb[cp][nt][ich], acc[mt][nt], 0, 0, 0);
        __builtin_amdgcn_s_setprio(0);
    }
#undef READ_FRAGS

    // epilogue: D row = quad*4 + r (oc), col = n
    int hrow = h0 + w;
    if (hrow < 62) {
#pragma unroll
        for (int mt = 0; mt < 4; ++mt) {
            float bias = Bp[mt * 4 + quad];
#pragma unroll
            for (int nt = 0; nt < 4; ++nt) {
                int wp = nt * 16 + col;
                if (wp < 62) {
#pragma unroll
                    for (int r = 0; r < 4; ++r) {
                        int oc = mt * 16 + quad * 4 + r;
                        out[(((size_t)nb * 64 + oc) * 30 + d) * 3844 + hrow * 62 + wp]
                            = acc[mt][nt][r] + bias;
                    }
                }
            }
        }
    }
}

extern "C" void kernel_launch(void* const* d_in, const int* in_sizes, int n_in,
                              void* d_out, int out_size, void* d_ws, size_t ws_size,
                              hipStream_t stream) {
    const float* x = (const float*)d_in[0];
    const float* W = (const float*)d_in[1];
    const float* Bp = (const float*)d_in[2];
    float* out = (float*)d_out;

    char* ws = (char*)d_ws;
    __hip_bfloat16* wT = (__hip_bfloat16*)ws;              // 221,184 B
    __hip_bfloat16* xT = (__hip_bfloat16*)(ws + 262144);   // 67,108,864 B

    build_wT<<<(27 * 64 * 64 + 255) / 256, 256, 0, stream>>>(W, wT);
    transpose_x<<<4 * 32 * 8, 256, 0, stream>>>(x, xT);
    conv_mfma<<<4 * 30 * 16, 256, 0, stream>>>(xT, wT, Bp, out);
}